// Round 17
// baseline (133.736 us; speedup 1.0000x reference)
//
#include <hip/hip_runtime.h>

#define TT    512
#define WW    257
#define HWSZ  (WW*WW)          // 66049
#define IMG2  (2*HWSZ)         // time stride in `output` (2 channels)
#define SCALE 3.5682482323055424f   // DT^-0.5 / gamma(1.5)
#define KD    163.84f               // KAPPA / DX^2

typedef short bf16x8 __attribute__((ext_vector_type(8)));
typedef short bf16x4 __attribute__((ext_vector_type(4)));
typedef float f32x4  __attribute__((ext_vector_type(4)));

__device__ __forceinline__ float wf(int j) {
    return sqrtf((float)(j + 1)) - sqrtf((float)j);
}
__device__ __forceinline__ float mcoef(int i, int k) {
    if (i == 0 || k > i) return 0.f;
    if (k == i) return 1.f;
    if (k == 0) return -wf(i - 1);
    int d = i - k;
    return wf(d) - wf(d - 1);
}
__device__ __forceinline__ unsigned short f2b(float f) {
    unsigned u = __float_as_uint(f);
    return (unsigned short)((u + 0x7FFFu + ((u >> 16) & 1u)) >> 16);
}
__device__ __forceinline__ float b2f(unsigned short h) {
    return __uint_as_float(((unsigned)h) << 16);
}
// async global->LDS, width 16: per-lane 16B-ALIGNED global src; dest = uniform base + lane*16
__device__ __forceinline__ void gl16(const float* g, float* l) {
    __builtin_amdgcn_global_load_lds((const __attribute__((address_space(1))) void*)g,
                                     (__attribute__((address_space(3))) void*)l, 16, 0, 0);
}

// ---- kernel 1: M as bf16 [512][512] (L2-resident); also zeroes d_out
__global__ __launch_bounds__(256)
void build_m(unsigned short* __restrict__ M, float* __restrict__ d_out) {
    int i = blockIdx.x;
    if (i == 0 && threadIdx.x == 0) *d_out = 0.f;
    for (int k = threadIdx.x; k < TT; k += 256)
        M[i * TT + k] = f2b(mcoef(i, k));
}

// ---- fused Y=2, WIDE-STAGED: chunk = 16 t, gl_lds dwordx4 staging (aligned-down),
// K=32 MFMA per chunk-pair. grid 512, 8 waves; wave w: i-tiles [32w,+32) & [480-32w,+32).
__global__ __launch_bounds__(512, 2)
void fused(const float* __restrict__ uin, const float* __restrict__ f1p,
           const float* __restrict__ lapk, const unsigned short* __restrict__ Mb,
           float* __restrict__ d_out)
{
    __shared__ float          uRaw[2][16][272];  // [buf][t-local][4 rows x 68 floats]
    __shared__ unsigned short uS[2][128][32];    // [pair][px'][32 t] swizzled
    __shared__ unsigned short sS[2][32][136];    // [pair][32 t][px']
    __shared__ float red[8];

    const int tid = threadIdx.x, w = tid >> 6, lane = tid & 63;
    const int lr = lane & 15, lg = lane >> 4;

    const int bid = blockIdx.x;                 // 512, XCD-bijective
    const int wg  = (bid & 7) * 64 + (bid >> 3);
    const int xt  = wg >> 7;
    const int ypb = wg & 127;
    const int Y0  = 1 + 2 * ypb;
    const int c0  = xt * 64;
    const bool validB = (Y0 + 1) <= 255;
    const bool pad    = (c0 + lane) == 255;

    const float ka = lapk[0], kb = lapk[1], kc = lapk[4];
    const int KA = (Y0 + c0) & 3;
    const int i00 = 32 * w, i01 = 480 - 32 * w;

    f32x4 acc0[8][2], acc1[8][2];
    #pragma unroll
    for (int a = 0; a < 8; ++a) {
        acc0[a][0] = (f32x4)0.f; acc0[a][1] = (f32x4)0.f;
        acc1[a][0] = (f32x4)0.f; acc1[a][1] = (f32x4)0.f;
    }

    const int rowmap  = lane / 17;              // 0..3
    const int quadmap = lane - rowmap * 17;     // 0..16
    const int etj = lane >> 3, eside = (lane >> 2) & 1, erj = lane & 3;

    float fvv[2][4];
    float eev[2];
    bf16x8 m0a, m0b, m1a, m1b;
    float lsum = 0.f;

    // issue chunk-k staging: 2 t x (1 main gl16 + 1 tail gl16 + 2 f1 dwords)
    auto ISSUE_STAGE = [&](int k, int b) {
        #pragma unroll
        for (int j = 0; j < 2; ++j) {
            const int t  = 16 * k + 2 * w + j;
            const int tl = 2 * w + j;
            size_t bl = (size_t)t * IMG2 + (size_t)(Y0 - 1 + rowmap) * WW + (c0 + 1);
            gl16(uin + (bl & ~(size_t)3) + 4 * quadmap, &uRaw[b][tl][0]);
            size_t b3 = (size_t)t * IMG2 + (size_t)(Y0 + 2) * WW + (c0 + 1);
            if (lane < 4)
                gl16(uin + (b3 & ~(size_t)3) + 4 * (13 + lane), &uRaw[b][tl][256]);
            size_t fb = (size_t)t * HWSZ + (size_t)Y0 * WW + (c0 + 1) + lane;
            fvv[b][2 * j]     = f1p[fb];
            fvv[b][2 * j + 1] = f1p[fb + WW];
        }
    };
    auto ISSUE_EE = [&](int K0, int eb) {   // edges for chunks K0..K0+3 (K0%4==0)
        const int t = 16 * (K0 + (etj >> 1)) + 2 * w + (etj & 1);
        eev[eb] = uin[(size_t)t * IMG2 + (size_t)(Y0 - 1 + erj) * WW + (eside ? c0 + 65 : c0)];
    };
    auto MLOAD = [&](int s) {               // clamped (uniform 4 b128)
        const int s0 = (s <= w) ? s : w;
        const int s1 = (s <= 15 - w) ? s : 15 - w;
        const unsigned short* mp0 = Mb + (size_t)(i00 + lr) * TT + 32 * s0 + 8 * lg;
        const unsigned short* mp1 = Mb + (size_t)(i01 + lr) * TT + 32 * s1 + 8 * lg;
        m0a = *(const bf16x8*)mp0; m0b = *(const bf16x8*)(mp0 + 16 * TT);
        m1a = *(const bf16x8*)mp1; m1b = *(const bf16x8*)(mp1 + 16 * TT);
    };

    auto STAGE = [&](int k, int b, int p, int e, int eb, int i4) {
        const float ee = eev[eb];
        float e1 = __shfl(ee, lane + 1, 64);
        float e2 = __shfl(ee, lane + 2, 64);
        float Qe = fmaf(ka, ee + e2, kb * e1);   // valid at erj<=1 lanes
        unsigned packA = 0, packB = 0;
        #pragma unroll
        for (int j = 0; j < 2; ++j) {
            const int t  = 16 * k + 2 * w + j;
            const int tl = 2 * w + j;
            const int aa0 = (2 * t + KA) & 3;
            const int aa1 = (aa0 + 1) & 3, aa2 = (aa0 + 2) & 3, aa3 = (aa0 + 3) & 3;
            float a0 = uRaw[b][tl][      lane + aa0];
            float a1 = uRaw[b][tl][ 68 + lane + aa1];
            float a2 = uRaw[b][tl][136 + lane + aa2];
            float a3 = uRaw[b][tl][204 + lane + aa3];
            float fA = fvv[b][2 * j], fB = fvv[b][2 * j + 1];
            float PA = a0 + a2, QA = fmaf(ka, PA, kb * a1), RA = fmaf(kb, PA, kc * a1);
            float PB = a1 + a3, QB = fmaf(ka, PB, kb * a2), RB = fmaf(kb, PB, kc * a2);
            float qmA = __shfl(QA, lane - 1, 64), qpA = __shfl(QA, lane + 1, 64);
            float qmB = __shfl(QB, lane - 1, 64), qpB = __shfl(QB, lane + 1, 64);
            const int tj = 2 * i4 + j;
            float eA0 = __shfl(Qe, 8 * tj, 64),     eA1 = __shfl(Qe, 8 * tj + 4, 64);
            float eB0 = __shfl(Qe, 8 * tj + 1, 64), eB1 = __shfl(Qe, 8 * tj + 5, 64);
            if (lane == 0)  { qmA = eA0; qmB = eB0; }
            if (lane == 63) { qpA = eA1; qpB = eB1; }
            float lapA = qmA + qpA + RA, lapB = qmB + qpB + RB;
            float sA  = a1 - fmaf(KD, lapA, fA);
            float sB_ = a2 - fmaf(KD, lapB, fB);
            unsigned short uAv = pad ? (unsigned short)0 : f2b(a1);
            unsigned short sAv = pad ? (unsigned short)0 : f2b(sA);
            unsigned short uBv = (pad || !validB) ? (unsigned short)0 : f2b(a2);
            unsigned short sBv = (pad || !validB) ? (unsigned short)0 : f2b(sB_);
            sS[p][16 * e + tl][lane]      = sAv;
            sS[p][16 * e + tl][64 + lane] = sBv;
            if (j == 0) { packA = uAv; packB = uBv; }
            else        { packA |= ((unsigned)uAv) << 16; packB |= ((unsigned)uBv) << 16; }
        }
        const unsigned off = (unsigned)((32 * e + 4 * w) ^ ((lane & 3) << 4));
        *(unsigned*)((char*)&uS[p][lane][0]      + off) = packA;
        *(unsigned*)((char*)&uS[p][64 + lane][0] + off) = packB;
    };

    auto MMA = [&](int s, int p) {
        bf16x8 af[8];
        #pragma unroll
        for (int mi = 0; mi < 8; ++mi)
            af[mi] = *(const bf16x8*)((char*)&uS[p][16 * mi + lr][0]
                                      + ((16 * lg) ^ ((lr & 3) << 4)));
        if (s <= w) {
            #pragma unroll
            for (int mi = 0; mi < 8; ++mi) {
                acc0[mi][0] = __builtin_amdgcn_mfma_f32_16x16x32_bf16(af[mi], m0a, acc0[mi][0], 0, 0, 0);
                acc0[mi][1] = __builtin_amdgcn_mfma_f32_16x16x32_bf16(af[mi], m0b, acc0[mi][1], 0, 0, 0);
            }
        }
        if (s <= 15 - w) {
            #pragma unroll
            for (int mi = 0; mi < 8; ++mi) {
                acc1[mi][0] = __builtin_amdgcn_mfma_f32_16x16x32_bf16(af[mi], m1a, acc1[mi][0], 0, 0, 0);
                acc1[mi][1] = __builtin_amdgcn_mfma_f32_16x16x32_bf16(af[mi], m1b, acc1[mi][1], 0, 0, 0);
            }
        }
    };

    auto EPI = [&](f32x4 (&acc)[8][2], int pp) {
        #pragma unroll
        for (int mi = 0; mi < 8; ++mi)
            #pragma unroll
            for (int nj = 0; nj < 2; ++nj) {
                bf16x4 sv = *(const bf16x4*)&sS[pp][16 * nj + lr][16 * mi + 4 * lg];
                #pragma unroll
                for (int r = 0; r < 4; ++r) {
                    float res = SCALE * acc[mi][nj][r] + b2f((unsigned short)sv[r]);
                    lsum += res * res;
                }
            }
    };

    // ---- prologue
    ISSUE_EE(0, 0);
    ISSUE_STAGE(0, 0);

    for (int kb = 0; kb < 4; ++kb) {
        #pragma unroll
        for (int jj = 0; jj < 8; ++jj) {
            const int k  = 8 * kb + jj;
            const int b  = jj & 1;              // uRaw/fvv buffer
            const int p  = (jj >> 1) & 1;       // uS/sS pair buffer
            const int e  = jj & 1;              // within-pair half
            const int eb = (jj >> 2) & 1;       // ee buffer
            const int i4 = jj & 3;

            if ((jj & 1) == 0) MLOAD(k >> 1);   // M for pair s, consumed at k+1
            if (k < 31) {
                if ((jj & 3) == 3) ISSUE_EE(k + 1, (jj == 3) ? 1 : 0);
                ISSUE_STAGE(k + 1, b ^ 1);
            }
            __builtin_amdgcn_sched_barrier(0);
            if (k == 31)             asm volatile("s_waitcnt vmcnt(0)");
            else if ((jj & 3) == 0)  asm volatile("s_waitcnt vmcnt(12)");
            else if ((jj & 3) == 1)  asm volatile("s_waitcnt vmcnt(8)");
            else if ((jj & 3) == 2)  asm volatile("s_waitcnt vmcnt(12)");
            else                     asm volatile("s_waitcnt vmcnt(9)");
            __builtin_amdgcn_sched_barrier(0);

            STAGE(k, b, p, e, eb, i4);

            __builtin_amdgcn_sched_barrier(0);
            asm volatile("s_waitcnt lgkmcnt(0)");
            __builtin_amdgcn_sched_barrier(0);
            __builtin_amdgcn_s_barrier();
            __builtin_amdgcn_sched_barrier(0);

            if (jj & 1) {
                MMA(k >> 1, p);
                if (k == 2 * w + 1)  EPI(acc0, w & 1);
                if (k == 31 - 2 * w) EPI(acc1, (15 - w) & 1);
            }
        }
    }

    // ---- reduce: wave shfl -> LDS -> one atomic per block
    #pragma unroll
    for (int off = 32; off > 0; off >>= 1)
        lsum += __shfl_down(lsum, off, 64);
    if (lane == 0) red[w] = lsum;
    __syncthreads();
    if (tid == 0) {
        float tot = 0.f;
        #pragma unroll
        for (int q = 0; q < 8; ++q) tot += red[q];
        atomicAdd(d_out, tot * (1.0f / 33292800.0f));
    }
}

extern "C" void kernel_launch(void* const* d_in, const int* in_sizes, int n_in,
                              void* d_out, int out_size, void* d_ws, size_t ws_size,
                              hipStream_t stream)
{
    const float* uin  = (const float*)d_in[0];
    const float* f1   = (const float*)d_in[1];
    const float* lapk = (const float*)d_in[2];
    float* out = (float*)d_out;

    unsigned short* Mb = (unsigned short*)d_ws;   // 512 KB

    build_m<<<dim3(TT), 256, 0, stream>>>(Mb, out);
    fused<<<dim3(512), 512, 0, stream>>>(uin, f1, lapk, Mb, out);
}

// Round 18
// 96.266 us; speedup vs baseline: 1.3892x; 1.3892x over previous
//
#include <hip/hip_runtime.h>

#define TT    512
#define WW    257
#define HWSZ  (WW*WW)          // 66049
#define IMG2  (2*HWSZ)         // time stride in `output` (2 channels)
#define SCALE 3.5682482323055424f   // DT^-0.5 / gamma(1.5)
#define KD    163.84f               // KAPPA / DX^2

typedef short bf16x8 __attribute__((ext_vector_type(8)));
typedef float f32x4  __attribute__((ext_vector_type(4)));
typedef unsigned int u32x4 __attribute__((ext_vector_type(4)));

__device__ __forceinline__ float wf(int j) {
    return sqrtf((float)(j + 1)) - sqrtf((float)j);
}
__device__ __forceinline__ float mcoef(int i, int k) {
    if (i == 0 || k > i) return 0.f;
    if (k == i) return 1.f;
    if (k == 0) return -wf(i - 1);
    int d = i - k;
    return wf(d) - wf(d - 1);
}
__device__ __forceinline__ unsigned short f2b(float f) {
    unsigned u = __float_as_uint(f);
    return (unsigned short)((u + 0x7FFFu + ((u >> 16) & 1u)) >> 16);
}
__device__ __forceinline__ unsigned pk2(float A, float B) {
    return (unsigned)f2b(A) | ((unsigned)f2b(B) << 16);
}
__device__ __forceinline__ float lo2f(unsigned u) { return __uint_as_float(u << 16); }
__device__ __forceinline__ float hi2f(unsigned u) { return __uint_as_float(u & 0xFFFF0000u); }

// ---- kernel 1: M as bf16 [512][512] (L2-resident); also zeroes d_out
__global__ __launch_bounds__(256)
void build_m(unsigned short* __restrict__ M, float* __restrict__ d_out) {
    int i = blockIdx.x;
    if (i == 0 && threadIdx.x == 0) *d_out = 0.f;
    for (int k = threadIdx.x; k < TT; k += 256)
        M[i * TT + k] = f2b(mcoef(i, k));
}

// ---- fused Y=2 (R15 skeleton) with packed-bf16 shuffles + edge table + packed sS.
// grid 512, 8 waves. Wave w: i-tiles [32w,32w+32) and [480-32w,512-32w).
__global__ __launch_bounds__(512, 2)
void fused(const float* __restrict__ uin, const float* __restrict__ f1p,
           const float* __restrict__ lapk, const unsigned short* __restrict__ Mb,
           float* __restrict__ d_out)
{
    __shared__ unsigned short uS[2][128][64];   // [buf][px''][t-local], px''=2px+row
    __shared__ unsigned       sS32[2][64][66];  // [buf][t-local][px-pair u32]
    __shared__ unsigned       eQ[2][8][16];     // [buf][wave][slot=2t+side] packed QeA|QeB
    __shared__ float red[8];

    const int tid  = threadIdx.x;
    const int w    = tid >> 6;
    const int lane = tid & 63;
    const int lr   = lane & 15;
    const int lg   = lane >> 4;

    const int bid = blockIdx.x;                 // 512, XCD-bijective
    const int wg  = (bid & 7) * 64 + (bid >> 3);
    const int xt  = wg >> 7;
    const int ypb = wg & 127;
    const int Y0  = 1 + 2 * ypb;
    const int c0  = xt * 64;
    const bool validB = (Y0 + 1) <= 255;
    const bool pad    = (c0 + lane) == 255;

    const float ka = lapk[0], kb = lapk[1], kc = lapk[4];

    f32x4 acc0[8][2], acc1[8][2];
    #pragma unroll
    for (int a = 0; a < 8; ++a) {
        acc0[a][0] = (f32x4)0.f; acc0[a][1] = (f32x4)0.f;
        acc1[a][0] = (f32x4)0.f; acc1[a][1] = (f32x4)0.f;
    }

    const int  i00 = 32 * w;
    const int  i01 = 480 - 32 * w;
    const int  ec0 = w >> 1;
    const int  ec1 = (15 - w) >> 1;
    float lsum = 0.f;

    // PF buffer: rows Y0-1..Y0+2 (a0..a3), f1 rows (fA,fB), edge gather ee
    float a0[8], a1[8], a2[8], a3[8], fA[8], fB[8], ee;
    // edge load map: lane = 8*tl + 4*side + row(0..3)
    const int etl = lane >> 3, eside = (lane >> 2) & 1, erow = lane & 3;
    const size_t geoff = (size_t)etl * IMG2 + (size_t)(Y0 - 1 + erow) * WW
                       + (eside ? c0 + 65 : c0);

    bf16x8 m0a[2], m0b[2], m1a[2], m1b[2];

    auto LOADR = [&](int c) {
        const int tb = 64 * c + 8 * w;
        const float* pu = uin + (size_t)tb * IMG2 + (size_t)(Y0 - 1) * WW + (c0 + 1) + lane;
        const float* pf = f1p + (size_t)tb * HWSZ + (size_t)Y0 * WW + (c0 + 1) + lane;
        #pragma unroll
        for (int rr = 0; rr < 8; ++rr) {
            const float* qu = pu + (size_t)rr * IMG2;
            a0[rr] = qu[0]; a1[rr] = qu[WW]; a2[rr] = qu[2 * WW]; a3[rr] = qu[3 * WW];
            fA[rr] = pf[(size_t)rr * HWSZ];
            fB[rr] = pf[(size_t)rr * HWSZ + WW];
        }
        ee = uin[(size_t)tb * IMG2 + geoff];
    };

    auto STAGE = [&](int b) {
        unsigned* eQw = &eQ[b][w][0];
        {   // edge table: slot l<16 = (t'=l>>1, side=l&1); 4 shuffles, 1 store
            const int sb8 = ((lane & 15) >> 1) * 8 + (lane & 1) * 4;
            float v0 = __shfl(ee, sb8, 64);
            float v1 = __shfl(ee, sb8 + 1, 64);
            float v2 = __shfl(ee, sb8 + 2, 64);
            float v3 = __shfl(ee, sb8 + 3, 64);
            float QeA = fmaf(ka, v0 + v2, kb * v1);
            float QeB = fmaf(ka, v1 + v3, kb * v2);
            if (lane < 16) eQw[lane] = pk2(QeA, QeB);
        }
        u32x4 upA, upB;
        #pragma unroll
        for (int rr = 0; rr < 8; ++rr) {
            float PA = a0[rr] + a2[rr];
            float QA = fmaf(ka, PA, kb * a1[rr]);
            float RA = fmaf(kb, PA, kc * a1[rr]);
            float PB = a1[rr] + a3[rr];
            float QB = fmaf(ka, PB, kb * a2[rr]);
            float RB = fmaf(kb, PB, kc * a2[rr]);
            unsigned Qp = pk2(QA, QB);                   // rows A|B packed
            unsigned pm = __shfl((int)Qp, lane - 1, 64); // one shuffle moves both rows
            unsigned pp = __shfl((int)Qp, lane + 1, 64);
            unsigned ep = eQw[2 * rr + (lane == 63 ? 1 : 0)];
            if (lane == 0)  pm = ep;
            if (lane == 63) pp = ep;
            float lapA = lo2f(pm) + lo2f(pp) + RA;
            float lapB = hi2f(pm) + hi2f(pp) + RB;
            float sA  = a1[rr] - fmaf(KD, lapA, fA[rr]);
            float sB_ = a2[rr] - fmaf(KD, lapB, fB[rr]);
            unsigned short sAv = pad ? (unsigned short)0 : f2b(sA);
            unsigned short sBv = (pad || !validB) ? (unsigned short)0 : f2b(sB_);
            sS32[b][8 * w + rr][lane] = (unsigned)sAv | ((unsigned)sBv << 16);
            unsigned short uAv = pad ? (unsigned short)0 : f2b(a1[rr]);
            unsigned short uBv = (pad || !validB) ? (unsigned short)0 : f2b(a2[rr]);
            if (rr & 1) { upA[rr >> 1] |= ((unsigned)uAv) << 16; upB[rr >> 1] |= ((unsigned)uBv) << 16; }
            else        { upA[rr >> 1]  = (unsigned)uAv;         upB[rr >> 1]  = (unsigned)uBv; }
        }
        const int swz = (w ^ (lane & 7)) * 8;
        *(u32x4*)&uS[b][2 * lane][swz]     = upA;   // px'' = 2px   (row A)
        *(u32x4*)&uS[b][2 * lane + 1][swz] = upB;   // px'' = 2px+1 (row B)
    };

    auto EPI = [&](f32x4 (&acc)[8][2], int b, int lbase) {
        #pragma unroll
        for (int mi = 0; mi < 8; ++mi)
            #pragma unroll
            for (int nj = 0; nj < 2; ++nj) {
                const unsigned* sp = &sS32[b][lbase + 16 * nj + lr][8 * mi + 2 * lg];
                unsigned s0 = sp[0], s1 = sp[1];
                f32x4 a = acc[mi][nj];
                float r0 = fmaf(SCALE, a[0], lo2f(s0));
                float r1 = fmaf(SCALE, a[1], hi2f(s0));
                float r2 = fmaf(SCALE, a[2], lo2f(s1));
                float r3 = fmaf(SCALE, a[3], hi2f(s1));
                lsum += r0 * r0 + r1 * r1 + r2 * r2 + r3 * r3;
            }
    };

    LOADR(0);
    for (int c = 0; c < 8; ++c) {
        const int b = c & 1;

        // M preload (predicated) BEFORE the burst: auto-waits never drain the burst
        #pragma unroll
        for (int sub = 0; sub < 2; ++sub) {
            const int s_ = 2 * c + sub;
            if (s_ <= w) {
                const unsigned short* mp0 = Mb + (size_t)(i00 + lr) * TT + 32 * s_ + 8 * lg;
                m0a[sub] = *(const bf16x8*)mp0; m0b[sub] = *(const bf16x8*)(mp0 + 16 * TT);
            }
            if (s_ <= 15 - w) {
                const unsigned short* mp1 = Mb + (size_t)(i01 + lr) * TT + 32 * s_ + 8 * lg;
                m1a[sub] = *(const bf16x8*)mp1; m1b[sub] = *(const bf16x8*)(mp1 + 16 * TT);
            }
        }
        __builtin_amdgcn_sched_barrier(0);

        STAGE(b);                       // consumes PF(c)
        if (c < 7) LOADR(c + 1);        // burst drains across barrier+MFMA

        __builtin_amdgcn_sched_barrier(0);
        asm volatile("s_waitcnt lgkmcnt(0)");
        __builtin_amdgcn_sched_barrier(0);
        __builtin_amdgcn_s_barrier();
        __builtin_amdgcn_sched_barrier(0);

        __builtin_amdgcn_s_setprio(1);
        #pragma unroll
        for (int sub = 0; sub < 2; ++sub) {
            const int s_ = 2 * c + sub;
            if (s_ <= w) {
                #pragma unroll
                for (int mi = 0; mi < 8; ++mi) {
                    bf16x8 a = *(const bf16x8*)&uS[b][16 * mi + lr][(((4 * sub + lg) ^ (lr & 7))) * 8];
                    acc0[mi][0] = __builtin_amdgcn_mfma_f32_16x16x32_bf16(a, m0a[sub], acc0[mi][0], 0, 0, 0);
                    acc0[mi][1] = __builtin_amdgcn_mfma_f32_16x16x32_bf16(a, m0b[sub], acc0[mi][1], 0, 0, 0);
                }
            }
            if (s_ <= 15 - w) {
                #pragma unroll
                for (int mi = 0; mi < 8; ++mi) {
                    bf16x8 a = *(const bf16x8*)&uS[b][16 * mi + lr][(((4 * sub + lg) ^ (lr & 7))) * 8];
                    acc1[mi][0] = __builtin_amdgcn_mfma_f32_16x16x32_bf16(a, m1a[sub], acc1[mi][0], 0, 0, 0);
                    acc1[mi][1] = __builtin_amdgcn_mfma_f32_16x16x32_bf16(a, m1b[sub], acc1[mi][1], 0, 0, 0);
                }
            }
        }
        __builtin_amdgcn_s_setprio(0);

        if (c == ec0) EPI(acc0, b, 32 * (w & 1));
        if (c == ec1) EPI(acc1, b, 32 * ((w + 1) & 1));
    }

    // ---- reduce: wave shfl -> LDS -> one atomic per block
    #pragma unroll
    for (int off = 32; off > 0; off >>= 1)
        lsum += __shfl_down(lsum, off, 64);
    if (lane == 0) red[w] = lsum;
    __syncthreads();
    if (tid == 0) {
        float tot = 0.f;
        #pragma unroll
        for (int q = 0; q < 8; ++q) tot += red[q];
        atomicAdd(d_out, tot * (1.0f / 33292800.0f));
    }
}

extern "C" void kernel_launch(void* const* d_in, const int* in_sizes, int n_in,
                              void* d_out, int out_size, void* d_ws, size_t ws_size,
                              hipStream_t stream)
{
    const float* uin  = (const float*)d_in[0];
    const float* f1   = (const float*)d_in[1];
    const float* lapk = (const float*)d_in[2];
    float* out = (float*)d_out;

    unsigned short* Mb = (unsigned short*)d_ws;   // 512 KB

    build_m<<<dim3(TT), 256, 0, stream>>>(Mb, out);
    fused<<<dim3(512), 512, 0, stream>>>(uin, f1, lapk, Mb, out);
}

// Round 19
// 95.206 us; speedup vs baseline: 1.4047x; 1.0111x over previous
//
#include <hip/hip_runtime.h>

#define TT    512
#define WW    257
#define HWSZ  (WW*WW)          // 66049
#define IMG2  (2*HWSZ)         // time stride in `output` (2 channels)
#define SCALE 3.5682482323055424f   // DT^-0.5 / gamma(1.5)
#define KD    163.84f               // KAPPA / DX^2

typedef short bf16x8 __attribute__((ext_vector_type(8)));
typedef short bf16x4 __attribute__((ext_vector_type(4)));
typedef float f32x4  __attribute__((ext_vector_type(4)));
typedef unsigned int u32x4 __attribute__((ext_vector_type(4)));

__device__ __forceinline__ float wf(int j) {
    return sqrtf((float)(j + 1)) - sqrtf((float)j);
}
__device__ __forceinline__ float mcoef(int i, int k) {
    if (i == 0 || k > i) return 0.f;
    if (k == i) return 1.f;
    if (k == 0) return -wf(i - 1);
    int d = i - k;
    return wf(d) - wf(d - 1);
}
__device__ __forceinline__ unsigned short f2b(float f) {
    unsigned u = __float_as_uint(f);
    return (unsigned short)((u + 0x7FFFu + ((u >> 16) & 1u)) >> 16);
}
__device__ __forceinline__ float b2f(unsigned short h) {
    return __uint_as_float(((unsigned)h) << 16);
}

// ---- kernel 1: M as bf16 [512][512] (L2-resident); also zeroes d_out
__global__ __launch_bounds__(256)
void build_m(unsigned short* __restrict__ M, float* __restrict__ d_out) {
    int i = blockIdx.x;
    if (i == 0 && threadIdx.x == 0) *d_out = 0.f;
    for (int k = threadIdx.x; k < TT; k += 256)
        M[i * TT + k] = f2b(mcoef(i, k));
}

// ---- fused Y=2: block = (y-pair, 64 px) x all 512 t. grid 512, 8 waves.
// Wave w: i-tiles [32w,32w+32) and [480-32w,512-32w) over 128 px' = 17 subs.
// M loads predicated; issue-order-aware waits; raw barrier (lgkmcnt only).
__global__ __launch_bounds__(512, 2)
void fused(const float* __restrict__ uin, const float* __restrict__ f1p,
           const float* __restrict__ lapk, const unsigned short* __restrict__ Mb,
           float* __restrict__ d_out)
{
    __shared__ unsigned short uS[2][128][64];   // [buf][px'][t-local] swizzled 16B segs
    __shared__ unsigned short sS[2][64][136];   // [buf][t-local][px' + pad]
    __shared__ float red[8];

    const int tid  = threadIdx.x;
    const int w    = tid >> 6;
    const int lane = tid & 63;
    const int lr   = lane & 15;
    const int lg   = lane >> 4;

    // XCD-bijective: consecutive wg = consecutive ypb within an x-tile
    const int bid = blockIdx.x;                 // 512
    const int wg  = (bid & 7) * 64 + (bid >> 3);
    const int xt  = wg >> 7;                    // 0..3
    const int ypb = wg & 127;                   // 0..127
    const int Y0  = 1 + 2 * ypb;                // first output row (second = Y0+1)
    const int c0  = xt * 64;
    const bool validB = (Y0 + 1) <= 255;

    const float ka = lapk[0], kb = lapk[1], kc = lapk[4];

    f32x4 acc0[8][2], acc1[8][2];
    #pragma unroll
    for (int a = 0; a < 8; ++a) {
        acc0[a][0] = (f32x4)0.f; acc0[a][1] = (f32x4)0.f;
        acc1[a][0] = (f32x4)0.f; acc1[a][1] = (f32x4)0.f;
    }

    const bool pad = (c0 + lane) == 255;        // image x == 256 (pad column)
    const int  i00 = 32 * w;
    const int  i01 = 480 - 32 * w;
    const int  ec0 = w >> 1;
    const int  ec1 = (15 - w) >> 1;
    float lsum = 0.f;

    // single PF buffer: rows Y0-1..Y0+2 (a0..a3), f1 rows Y0,Y0+1, edge gather
    float a0[8], a1[8], a2[8], a3[8], fA[8], fB[8], ee;
    // edge map: lane = 8*tl + 4*side + rj  (tl = t-local, rj = row offset 0..3)
    const int tl = lane >> 3, code = lane & 7, side = code >> 2, rj = code & 3;
    const size_t geoff = (size_t)tl * IMG2 + (size_t)(Y0 - 1 + rj) * WW
                       + (side ? c0 + 65 : c0);

    auto LOADR = [&](int c) {
        const int tb = 64 * c + 8 * w;
        const float* pu = uin + (size_t)tb * IMG2 + (size_t)(Y0 - 1) * WW + (c0 + 1) + lane;
        const float* pf = f1p + (size_t)tb * HWSZ + (size_t)Y0 * WW + (c0 + 1) + lane;
        #pragma unroll
        for (int rr = 0; rr < 8; ++rr) {
            const float* qu = pu + (size_t)rr * IMG2;
            a0[rr] = qu[0]; a1[rr] = qu[WW]; a2[rr] = qu[2 * WW]; a3[rr] = qu[3 * WW];
            fA[rr] = pf[(size_t)rr * HWSZ];
            fB[rr] = pf[(size_t)rr * HWSZ + WW];
        }
        ee = uin[(size_t)tb * IMG2 + geoff];
    };

    auto STAGE = [&](int b) {
        // Qe at lane 8tl+4side+rj = edge Q starting at row rj (valid rj<=1)
        float e1  = __shfl(ee, lane + 1, 64);
        float e2  = __shfl(ee, lane + 2, 64);
        float QeX = fmaf(ka, ee + e2, kb * e1);
        u32x4 upA, upB;
        #pragma unroll
        for (int rr = 0; rr < 8; ++rr) {
            float PA = a0[rr] + a2[rr];
            float QA = fmaf(ka, PA, kb * a1[rr]);
            float RA = fmaf(kb, PA, kc * a1[rr]);
            float PB = a1[rr] + a3[rr];
            float QB = fmaf(ka, PB, kb * a2[rr]);
            float RB = fmaf(kb, PB, kc * a2[rr]);
            float qmA = __shfl(QA, lane - 1, 64), qpA = __shfl(QA, lane + 1, 64);
            float qmB = __shfl(QB, lane - 1, 64), qpB = __shfl(QB, lane + 1, 64);
            float eA0 = __shfl(QeX, 8 * rr,     64), eA1 = __shfl(QeX, 8 * rr + 4, 64);
            float eB0 = __shfl(QeX, 8 * rr + 1, 64), eB1 = __shfl(QeX, 8 * rr + 5, 64);
            if (lane == 0)  { qmA = eA0; qmB = eB0; }
            if (lane == 63) { qpA = eA1; qpB = eB1; }
            float lapA = qmA + qpA + RA;
            float lapB = qmB + qpB + RB;
            float sA = a1[rr] - fmaf(KD, lapA, fA[rr]);
            float sB_ = a2[rr] - fmaf(KD, lapB, fB[rr]);
            unsigned short uAv = pad ? (unsigned short)0 : f2b(a1[rr]);
            unsigned short sAv = pad ? (unsigned short)0 : f2b(sA);
            unsigned short uBv = (pad || !validB) ? (unsigned short)0 : f2b(a2[rr]);
            unsigned short sBv = (pad || !validB) ? (unsigned short)0 : f2b(sB_);
            sS[b][8 * w + rr][lane]      = sAv;
            sS[b][8 * w + rr][64 + lane] = sBv;
            if (rr & 1) { upA[rr >> 1] |= ((unsigned)uAv) << 16; upB[rr >> 1] |= ((unsigned)uBv) << 16; }
            else        { upA[rr >> 1]  = (unsigned)uAv;         upB[rr >> 1]  = (unsigned)uBv; }
        }
        *(u32x4*)&uS[b][lane]     [(w ^ (lane & 7)) * 8] = upA;
        *(u32x4*)&uS[b][64 + lane][(w ^ (lane & 7)) * 8] = upB;
    };

    auto EPI = [&](f32x4 (&acc)[8][2], int b, int lbase) {
        #pragma unroll
        for (int mi = 0; mi < 8; ++mi)
            #pragma unroll
            for (int nj = 0; nj < 2; ++nj) {
                bf16x4 sv = *(const bf16x4*)&sS[b][lbase + 16 * nj + lr][16 * mi + 4 * lg];
                #pragma unroll
                for (int r = 0; r < 4; ++r) {
                    float res = SCALE * acc[mi][nj][r] + b2f((unsigned short)sv[r]);
                    lsum += res * res;
                }
            }
    };

    LOADR(0);
    for (int c = 0; c < 8; ++c) {
        const int b = c & 1;

        // M preload (PREDICATED — only tiles this wave still accumulates).
        // Issued before the 49-load burst so auto-waits never drain it.
        bf16x8 m0a[2], m0b[2], m1a[2], m1b[2];
        #pragma unroll
        for (int sub = 0; sub < 2; ++sub) {
            const int s_ = 2 * c + sub;
            if (s_ <= w) {
                const unsigned short* mp0 = Mb + (size_t)(i00 + lr) * TT + 32 * s_ + 8 * lg;
                m0a[sub] = *(const bf16x8*)mp0; m0b[sub] = *(const bf16x8*)(mp0 + 16 * TT);
            }
            if (s_ <= 15 - w) {
                const unsigned short* mp1 = Mb + (size_t)(i01 + lr) * TT + 32 * s_ + 8 * lg;
                m1a[sub] = *(const bf16x8*)mp1; m1b[sub] = *(const bf16x8*)(mp1 + 16 * TT);
            }
        }
        __builtin_amdgcn_sched_barrier(0);

        STAGE(b);                       // consumes PF(c); auto-wait leaves M in flight
        if (c < 7) LOADR(c + 1);        // 49-load burst, drains across barrier+MFMA

        __builtin_amdgcn_sched_barrier(0);
        asm volatile("s_waitcnt lgkmcnt(0)");
        __builtin_amdgcn_sched_barrier(0);
        __builtin_amdgcn_s_barrier();
        __builtin_amdgcn_sched_barrier(0);

        __builtin_amdgcn_s_setprio(1);
        #pragma unroll
        for (int sub = 0; sub < 2; ++sub) {
            const int s_ = 2 * c + sub;
            if (s_ <= w) {
                #pragma unroll
                for (int mi = 0; mi < 8; ++mi) {
                    bf16x8 a = *(const bf16x8*)&uS[b][16 * mi + lr][(((4 * sub + lg) ^ (lr & 7))) * 8];
                    acc0[mi][0] = __builtin_amdgcn_mfma_f32_16x16x32_bf16(a, m0a[sub], acc0[mi][0], 0, 0, 0);
                    acc0[mi][1] = __builtin_amdgcn_mfma_f32_16x16x32_bf16(a, m0b[sub], acc0[mi][1], 0, 0, 0);
                }
            }
            if (s_ <= 15 - w) {
                #pragma unroll
                for (int mi = 0; mi < 8; ++mi) {
                    bf16x8 a = *(const bf16x8*)&uS[b][16 * mi + lr][(((4 * sub + lg) ^ (lr & 7))) * 8];
                    acc1[mi][0] = __builtin_amdgcn_mfma_f32_16x16x32_bf16(a, m1a[sub], acc1[mi][0], 0, 0, 0);
                    acc1[mi][1] = __builtin_amdgcn_mfma_f32_16x16x32_bf16(a, m1b[sub], acc1[mi][1], 0, 0, 0);
                }
            }
        }
        __builtin_amdgcn_s_setprio(0);

        if (c == ec0) EPI(acc0, b, 32 * (w & 1));
        if (c == ec1) EPI(acc1, b, 32 * ((w + 1) & 1));
    }

    // ---- reduce: wave shfl -> LDS -> one atomic per block
    #pragma unroll
    for (int off = 32; off > 0; off >>= 1)
        lsum += __shfl_down(lsum, off, 64);
    if (lane == 0) red[w] = lsum;
    __syncthreads();
    if (tid == 0) {
        float tot = 0.f;
        #pragma unroll
        for (int q = 0; q < 8; ++q) tot += red[q];
        atomicAdd(d_out, tot * (1.0f / 33292800.0f));
    }
}

extern "C" void kernel_launch(void* const* d_in, const int* in_sizes, int n_in,
                              void* d_out, int out_size, void* d_ws, size_t ws_size,
                              hipStream_t stream)
{
    const float* uin  = (const float*)d_in[0];
    const float* f1   = (const float*)d_in[1];
    const float* lapk = (const float*)d_in[2];
    float* out = (float*)d_out;

    unsigned short* Mb = (unsigned short*)d_ws;   // 512 KB

    build_m<<<dim3(TT), 256, 0, stream>>>(Mb, out);
    fused<<<dim3(512), 512, 0, stream>>>(uin, f1, lapk, Mb, out);
}